// Round 1
// baseline (404.568 us; speedup 1.0000x reference)
//
#include <hip/hip_runtime.h>
#include <math.h>

// MS-SSIM loss, fp32, (32,3,384,384), 5 scales, win=11 sigma=1.5, VALID.
// Strategy: per-scale fused tile kernel: LDS patch (42x42) -> hblur of
// {X,Y,XX,YY,XY} -> vblur + ssim/cs map -> block reduce -> atomicAdd into
// per-image accumulators. 2x2 avg-pool kernels build pyramid in d_ws.

namespace {

constexpr int NIMG = 96;            // B*C = 32*3
constexpr float C1c = 6.5025f;      // (0.01*255)^2
constexpr float C2c = 58.5225f;     // (0.03*255)^2

__device__ __forceinline__ void make_gauss(float g[11]) {
  float s = 0.f;
#pragma unroll
  for (int i = 0; i < 11; ++i) {
    float d = (float)(i - 5);
    g[i] = expf(-(d * d) / 4.5f);   // 2*sigma^2 = 4.5
    s += g[i];
  }
#pragma unroll
  for (int i = 0; i < 11; ++i) g[i] /= s;
}

template <int H, int W>
__global__ __launch_bounds__(256) void ssim_kernel(
    const float* __restrict__ X, const float* __restrict__ Y,
    float* __restrict__ accSsim, float* __restrict__ accCs) {
  constexpr int OH = H - 10, OW = W - 10;
  constexpr int TS = 32;            // output tile
  constexpr int PS = TS + 10;       // input patch = 42
  __shared__ float sX[PS][PS + 2];
  __shared__ float sY[PS][PS + 2];
  __shared__ float hb[5][PS][TS + 1];
  __shared__ float red[2][4];

  const int img = blockIdx.z;
  const int ox0 = blockIdx.x * TS, oy0 = blockIdx.y * TS;
  const int tid = threadIdx.x;

  float g[11];
  make_gauss(g);

  const float* Xi = X + (size_t)img * H * W;
  const float* Yi = Y + (size_t)img * H * W;

  // Load patch (clamped at borders; clamped values never feed valid outputs).
  for (int i = tid; i < PS * PS; i += 256) {
    int r = i / PS, c = i - r * PS;
    int gr = oy0 + r; if (gr > H - 1) gr = H - 1;
    int gc = ox0 + c; if (gc > W - 1) gc = W - 1;
    sX[r][c] = Xi[gr * W + gc];
    sY[r][c] = Yi[gr * W + gc];
  }
  __syncthreads();

  // Horizontal blur of 5 channels: PS rows x TS cols.
  for (int i = tid; i < PS * TS; i += 256) {
    int r = i / TS, c = i - r * TS;
    float ax = 0, ay = 0, axx = 0, ayy = 0, axy = 0;
#pragma unroll
    for (int k = 0; k < 11; ++k) {
      float w = g[k];
      float x = sX[r][c + k], y = sY[r][c + k];
      ax += w * x; ay += w * y;
      axx += w * x * x; ayy += w * y * y; axy += w * x * y;
    }
    hb[0][r][c] = ax; hb[1][r][c] = ay; hb[2][r][c] = axx;
    hb[3][r][c] = ayy; hb[4][r][c] = axy;
  }
  __syncthreads();

  // Vertical blur + SSIM/CS map + per-thread accumulate.
  float ssim_s = 0.f, cs_s = 0.f;
  for (int i = tid; i < TS * TS; i += 256) {
    int r = i / TS, c = i - r * TS;
    if (oy0 + r < OH && ox0 + c < OW) {
      float mu1 = 0, mu2 = 0, mxx = 0, myy = 0, mxy = 0;
#pragma unroll
      for (int k = 0; k < 11; ++k) {
        float w = g[k];
        mu1 += w * hb[0][r + k][c];
        mu2 += w * hb[1][r + k][c];
        mxx += w * hb[2][r + k][c];
        myy += w * hb[3][r + k][c];
        mxy += w * hb[4][r + k][c];
      }
      float mu1sq = mu1 * mu1, mu2sq = mu2 * mu2, mu12 = mu1 * mu2;
      float s1 = mxx - mu1sq, s2 = myy - mu2sq, s12 = mxy - mu12;
      float cs = (2.f * s12 + C2c) / (s1 + s2 + C2c);
      float ss = ((2.f * mu12 + C1c) / (mu1sq + mu2sq + C1c)) * cs;
      cs_s += cs; ssim_s += ss;
    }
  }

  // Wave64 shuffle reduce, then cross-wave via LDS, then 2 atomics/block.
#pragma unroll
  for (int off = 32; off > 0; off >>= 1) {
    ssim_s += __shfl_down(ssim_s, off);
    cs_s   += __shfl_down(cs_s, off);
  }
  int wave = tid >> 6, lane = tid & 63;
  if (lane == 0) { red[0][wave] = ssim_s; red[1][wave] = cs_s; }
  __syncthreads();
  if (tid == 0) {
    atomicAdd(&accSsim[img], red[0][0] + red[0][1] + red[0][2] + red[0][3]);
    atomicAdd(&accCs[img],   red[1][0] + red[1][1] + red[1][2] + red[1][3]);
  }
}

__global__ __launch_bounds__(256) void downsample2(
    const float* __restrict__ X, const float* __restrict__ Y,
    float* __restrict__ Xo, float* __restrict__ Yo, int Hi, int Wi) {
  int Ho = Hi >> 1, Wo = Wi >> 1;
  int total = NIMG * Ho * Wo;
  for (int i = blockIdx.x * 256 + threadIdx.x; i < total;
       i += gridDim.x * 256) {
    int w = i % Wo; int t = i / Wo; int h = t % Ho; int img = t / Ho;
    const float* xi = X + (size_t)img * Hi * Wi;
    const float* yi = Y + (size_t)img * Hi * Wi;
    int r = 2 * h, c = 2 * w;
    Xo[i] = 0.25f * (xi[r * Wi + c] + xi[r * Wi + c + 1] +
                     xi[(r + 1) * Wi + c] + xi[(r + 1) * Wi + c + 1]);
    Yo[i] = 0.25f * (yi[r * Wi + c] + yi[r * Wi + c + 1] +
                     yi[(r + 1) * Wi + c] + yi[(r + 1) * Wi + c + 1]);
  }
}

__global__ void zero_acc(float* __restrict__ p, int n) {
  int i = blockIdx.x * 256 + threadIdx.x;
  if (i < n) p[i] = 0.f;
}

// acc layout: acc[s*2+0][img] = ssim sum, acc[s*2+1][img] = cs sum.
__global__ void final_kernel(const float* __restrict__ acc,
                             float* __restrict__ out) {
  __shared__ float prods[NIMG];
  const float wts[5] = {0.0448f, 0.2856f, 0.3001f, 0.2363f, 0.1333f};
  const float inv_npix[5] = {1.f / (374.f * 374.f), 1.f / (182.f * 182.f),
                             1.f / (86.f * 86.f),  1.f / (38.f * 38.f),
                             1.f / (14.f * 14.f)};
  int t = threadIdx.x;
  if (t < NIMG) {
    float p = 1.f;
#pragma unroll
    for (int s = 0; s < 5; ++s) {
      float sum = (s < 4) ? acc[(s * 2 + 1) * NIMG + t]
                          : acc[(s * 2 + 0) * NIMG + t];
      float m = sum * inv_npix[s];
      m = m > 0.f ? m : 0.f;
      p *= powf(m, wts[s]);
    }
    prods[t] = p;
  }
  __syncthreads();
  if (t == 0) {
    float s = 0.f;
    for (int i = 0; i < NIMG; ++i) s += prods[i];
    out[0] = 1.f - s / (float)NIMG;
  }
}

}  // namespace

extern "C" void kernel_launch(void* const* d_in, const int* in_sizes, int n_in,
                              void* d_out, int out_size, void* d_ws,
                              size_t ws_size, hipStream_t stream) {
  const float* X0 = (const float*)d_in[0];
  const float* Y0 = (const float*)d_in[1];
  float* out = (float*)d_out;
  float* ws = (float*)d_ws;

  const size_t L1 = (size_t)NIMG * 192 * 192;
  const size_t L2 = (size_t)NIMG * 96 * 96;
  const size_t L3 = (size_t)NIMG * 48 * 48;
  const size_t L4 = (size_t)NIMG * 24 * 24;

  float* x1 = ws;
  float* x2 = x1 + L1;
  float* x3 = x2 + L2;
  float* x4 = x3 + L3;
  float* y1 = x4 + L4;
  float* y2 = y1 + L1;
  float* y3 = y2 + L2;
  float* y4 = y3 + L3;
  float* acc = y4 + L4;  // 5*2*96 floats

  zero_acc<<<dim3(4), dim3(256), 0, stream>>>(acc, 10 * NIMG);

  auto dsgrid = [](size_t total) {
    return dim3((unsigned)((total + 255) / 256));
  };

  // Scale 0
  ssim_kernel<384, 384><<<dim3(12, 12, NIMG), dim3(256), 0, stream>>>(
      X0, Y0, acc + 0 * NIMG, acc + 1 * NIMG);
  downsample2<<<dsgrid(L1), dim3(256), 0, stream>>>(X0, Y0, x1, y1, 384, 384);
  // Scale 1
  ssim_kernel<192, 192><<<dim3(6, 6, NIMG), dim3(256), 0, stream>>>(
      x1, y1, acc + 2 * NIMG, acc + 3 * NIMG);
  downsample2<<<dsgrid(L2), dim3(256), 0, stream>>>(x1, y1, x2, y2, 192, 192);
  // Scale 2
  ssim_kernel<96, 96><<<dim3(3, 3, NIMG), dim3(256), 0, stream>>>(
      x2, y2, acc + 4 * NIMG, acc + 5 * NIMG);
  downsample2<<<dsgrid(L3), dim3(256), 0, stream>>>(x2, y2, x3, y3, 96, 96);
  // Scale 3
  ssim_kernel<48, 48><<<dim3(2, 2, NIMG), dim3(256), 0, stream>>>(
      x3, y3, acc + 6 * NIMG, acc + 7 * NIMG);
  downsample2<<<dsgrid(L4), dim3(256), 0, stream>>>(x3, y3, x4, y4, 48, 48);
  // Scale 4
  ssim_kernel<24, 24><<<dim3(1, 1, NIMG), dim3(256), 0, stream>>>(
      x4, y4, acc + 8 * NIMG, acc + 9 * NIMG);

  final_kernel<<<dim3(1), dim3(128), 0, stream>>>(acc, out);
}

// Round 2
// 349.083 us; speedup vs baseline: 1.1589x; 1.1589x over previous
//
#include <hip/hip_runtime.h>
#include <math.h>

// MS-SSIM loss, fp32, (32,3,384,384), 5 scales, win=11 sigma=1.5, VALID.
// R2: constexpr gaussian weights (no expf), sliding-window multi-output
// blur phases (4 outputs/thread, each input read once), vectorized LDS,
// fused 4-level pyramid kernel (one launch instead of 4 downsamples).

namespace {

constexpr int NIMG = 96;            // B*C = 32*3
constexpr float C1c = 6.5025f;      // (0.01*255)^2
constexpr float C2c = 58.5225f;     // (0.03*255)^2

// gauss(11, sigma=1.5), normalized; computed in double, matches expf path.
__device__ constexpr float GW[11] = {
    0.00102838f, 0.00759875f, 0.03600077f, 0.10936070f, 0.21300553f,
    0.26601172f,
    0.21300553f, 0.10936070f, 0.03600077f, 0.00759875f, 0.00102838f};

template <int H, int W>
__global__ __launch_bounds__(256) void ssim_kernel(
    const float* __restrict__ X, const float* __restrict__ Y,
    float* __restrict__ accSsim, float* __restrict__ accCs) {
  constexpr int OH = H - 10, OW = W - 10;
  constexpr int TS = 32;            // output tile 32x32
  constexpr int PS = TS + 10;       // input patch 42

  __shared__ __align__(16) float sP[2][PS][48];   // X,Y patch, padded rows
  __shared__ __align__(16) float hb[5][PS][36];   // hblurred channels
  __shared__ float red[2][4];

  const int img = blockIdx.z;
  const int ox0 = blockIdx.x * TS, oy0 = blockIdx.y * TS;
  const int tid = threadIdx.x;

  const float* Xi = X + (size_t)img * H * W;
  const float* Yi = Y + (size_t)img * H * W;

  // ---- Phase 1: load 42x44 patch (float4 fast path, clamped at edges) ----
  for (int t = tid; t < PS * 11; t += 256) {
    int r = t / 11, q = t - r * 11;
    int gr = oy0 + r; if (gr > H - 1) gr = H - 1;
    int gc0 = ox0 + 4 * q;
    float4 vx, vy;
    if (gc0 + 3 <= W - 1) {
      vx = *(const float4*)&Xi[(size_t)gr * W + gc0];
      vy = *(const float4*)&Yi[(size_t)gr * W + gc0];
    } else {
      int c0 = gc0 > W - 1 ? W - 1 : gc0;
      int c1 = gc0 + 1 > W - 1 ? W - 1 : gc0 + 1;
      int c2 = gc0 + 2 > W - 1 ? W - 1 : gc0 + 2;
      int c3 = gc0 + 3 > W - 1 ? W - 1 : gc0 + 3;
      const float* xr = &Xi[(size_t)gr * W];
      const float* yr = &Yi[(size_t)gr * W];
      vx = make_float4(xr[c0], xr[c1], xr[c2], xr[c3]);
      vy = make_float4(yr[c0], yr[c1], yr[c2], yr[c3]);
    }
    *(float4*)&sP[0][r][4 * q] = vx;
    *(float4*)&sP[1][r][4 * q] = vy;
  }
  __syncthreads();

  // ---- Phase 2: horizontal blur, 4 outputs per task, sliding window ----
  for (int t = tid; t < PS * 8; t += 256) {
    int r = t >> 3, c0 = (t & 7) * 4;
    const float* rx = &sP[0][r][c0];
    const float* ry = &sP[1][r][c0];
    float4 x0 = *(const float4*)rx;
    float4 x1 = *(const float4*)(rx + 4);
    float4 x2 = *(const float4*)(rx + 8);
    float2 x3 = *(const float2*)(rx + 12);
    float4 y0 = *(const float4*)ry;
    float4 y1 = *(const float4*)(ry + 4);
    float4 y2 = *(const float4*)(ry + 8);
    float2 y3 = *(const float2*)(ry + 12);
    float px[14] = {x0.x, x0.y, x0.z, x0.w, x1.x, x1.y, x1.z, x1.w,
                    x2.x, x2.y, x2.z, x2.w, x3.x, x3.y};
    float py[14] = {y0.x, y0.y, y0.z, y0.w, y1.x, y1.y, y1.z, y1.w,
                    y2.x, y2.y, y2.z, y2.w, y3.x, y3.y};
    float a0[4] = {0, 0, 0, 0}, a1[4] = {0, 0, 0, 0}, a2[4] = {0, 0, 0, 0},
          a3[4] = {0, 0, 0, 0}, a4[4] = {0, 0, 0, 0};
#pragma unroll
    for (int j = 0; j < 14; ++j) {
      float x = px[j], y = py[j];
      float xx = x * x, yy = y * y, xy = x * y;
#pragma unroll
      for (int i = 0; i < 4; ++i) {
        constexpr int lo = 0;  (void)lo;
        int k = j - i;
        if (k >= 0 && k <= 10) {
          float wt = GW[k];
          a0[i] += wt * x;  a1[i] += wt * y;
          a2[i] += wt * xx; a3[i] += wt * yy; a4[i] += wt * xy;
        }
      }
    }
    *(float4*)&hb[0][r][c0] = make_float4(a0[0], a0[1], a0[2], a0[3]);
    *(float4*)&hb[1][r][c0] = make_float4(a1[0], a1[1], a1[2], a1[3]);
    *(float4*)&hb[2][r][c0] = make_float4(a2[0], a2[1], a2[2], a2[3]);
    *(float4*)&hb[3][r][c0] = make_float4(a3[0], a3[1], a3[2], a3[3]);
    *(float4*)&hb[4][r][c0] = make_float4(a4[0], a4[1], a4[2], a4[3]);
  }
  __syncthreads();

  // ---- Phase 3: vertical blur (4 rows/thread) + ssim map + accumulate ----
  const int c = tid & 31, r0 = (tid >> 5) * 4;
  float b0[4] = {0, 0, 0, 0}, b1[4] = {0, 0, 0, 0}, b2[4] = {0, 0, 0, 0},
        b3[4] = {0, 0, 0, 0}, b4[4] = {0, 0, 0, 0};
#pragma unroll
  for (int j = 0; j < 14; ++j) {
    float v0 = hb[0][r0 + j][c], v1 = hb[1][r0 + j][c], v2 = hb[2][r0 + j][c],
          v3 = hb[3][r0 + j][c], v4 = hb[4][r0 + j][c];
#pragma unroll
    for (int i = 0; i < 4; ++i) {
      int k = j - i;
      if (k >= 0 && k <= 10) {
        float wt = GW[k];
        b0[i] += wt * v0; b1[i] += wt * v1; b2[i] += wt * v2;
        b3[i] += wt * v3; b4[i] += wt * v4;
      }
    }
  }
  float ssim_s = 0.f, cs_s = 0.f;
#pragma unroll
  for (int i = 0; i < 4; ++i) {
    if (oy0 + r0 + i < OH && ox0 + c < OW) {
      float mu1 = b0[i], mu2 = b1[i];
      float mu1sq = mu1 * mu1, mu2sq = mu2 * mu2, mu12 = mu1 * mu2;
      float s1 = b2[i] - mu1sq, s2 = b3[i] - mu2sq, s12 = b4[i] - mu12;
      float cs = (2.f * s12 + C2c) / (s1 + s2 + C2c);
      float ss = ((2.f * mu12 + C1c) / (mu1sq + mu2sq + C1c)) * cs;
      cs_s += cs; ssim_s += ss;
    }
  }

#pragma unroll
  for (int off = 32; off > 0; off >>= 1) {
    ssim_s += __shfl_down(ssim_s, off);
    cs_s   += __shfl_down(cs_s, off);
  }
  int wave = tid >> 6, lane = tid & 63;
  if (lane == 0) { red[0][wave] = ssim_s; red[1][wave] = cs_s; }
  __syncthreads();
  if (tid == 0) {
    atomicAdd(&accSsim[img], red[0][0] + red[0][1] + red[0][2] + red[0][3]);
    atomicAdd(&accCs[img],   red[1][0] + red[1][1] + red[1][2] + red[1][3]);
  }
}

// One launch builds all 4 pyramid levels for X and Y.
// avg_pool2 composed k times == average over 2^k x 2^k blocks (exactly the
// same tree of /4 averages as the reference's repeated pooling).
__global__ __launch_bounds__(256) void pyramid_kernel(
    const float* __restrict__ X, const float* __restrict__ Y,
    float* __restrict__ x1, float* __restrict__ y1,
    float* __restrict__ x2, float* __restrict__ y2,
    float* __restrict__ x3, float* __restrict__ y3,
    float* __restrict__ x4, float* __restrict__ y4) {
  __shared__ float s1[16][17];
  __shared__ float s2[8][9];
  __shared__ float s3[4][5];
  const int img = blockIdx.z;
  const int gx0 = blockIdx.x * 32, gy0 = blockIdx.y * 32;
  const int t = threadIdx.x;
  const int r = t >> 4, ccol = t & 15;

  const float* src[2] = {X + (size_t)img * 384 * 384,
                         Y + (size_t)img * 384 * 384};
  float* o1[2] = {x1 + (size_t)img * 192 * 192, y1 + (size_t)img * 192 * 192};
  float* o2[2] = {x2 + (size_t)img * 96 * 96,   y2 + (size_t)img * 96 * 96};
  float* o3[2] = {x3 + (size_t)img * 48 * 48,   y3 + (size_t)img * 48 * 48};
  float* o4[2] = {x4 + (size_t)img * 24 * 24,   y4 + (size_t)img * 24 * 24};

  for (int ch = 0; ch < 2; ++ch) {
    const float* S = src[ch];
    int gr = gy0 + 2 * r, gc = gx0 + 2 * ccol;
    float2 u = *(const float2*)&S[(size_t)gr * 384 + gc];
    float2 v = *(const float2*)&S[(size_t)(gr + 1) * 384 + gc];
    float l1 = 0.25f * (u.x + u.y + v.x + v.y);
    o1[ch][(size_t)(gy0 / 2 + r) * 192 + gx0 / 2 + ccol] = l1;
    s1[r][ccol] = l1;
    __syncthreads();
    if (t < 64) {
      int r2 = t >> 3, c2 = t & 7;
      float l2 = 0.25f * (s1[2 * r2][2 * c2] + s1[2 * r2][2 * c2 + 1] +
                          s1[2 * r2 + 1][2 * c2] + s1[2 * r2 + 1][2 * c2 + 1]);
      o2[ch][(size_t)(gy0 / 4 + r2) * 96 + gx0 / 4 + c2] = l2;
      s2[r2][c2] = l2;
    }
    __syncthreads();
    if (t < 16) {
      int r3 = t >> 2, c3 = t & 3;
      float l3 = 0.25f * (s2[2 * r3][2 * c3] + s2[2 * r3][2 * c3 + 1] +
                          s2[2 * r3 + 1][2 * c3] + s2[2 * r3 + 1][2 * c3 + 1]);
      o3[ch][(size_t)(gy0 / 8 + r3) * 48 + gx0 / 8 + c3] = l3;
      s3[r3][c3] = l3;
    }
    __syncthreads();
    if (t < 4) {
      int r4 = t >> 1, c4 = t & 1;
      float l4 = 0.25f * (s3[2 * r4][2 * c4] + s3[2 * r4][2 * c4 + 1] +
                          s3[2 * r4 + 1][2 * c4] + s3[2 * r4 + 1][2 * c4 + 1]);
      o4[ch][(size_t)(gy0 / 16 + r4) * 24 + gx0 / 16 + c4] = l4;
    }
    __syncthreads();
  }
}

__global__ void zero_acc(float* __restrict__ p, int n) {
  int i = blockIdx.x * 256 + threadIdx.x;
  if (i < n) p[i] = 0.f;
}

// acc layout: acc[s*2+0][img] = ssim sum, acc[s*2+1][img] = cs sum.
__global__ void final_kernel(const float* __restrict__ acc,
                             float* __restrict__ out) {
  __shared__ float prods[NIMG];
  const float wts[5] = {0.0448f, 0.2856f, 0.3001f, 0.2363f, 0.1333f};
  const float inv_npix[5] = {1.f / (374.f * 374.f), 1.f / (182.f * 182.f),
                             1.f / (86.f * 86.f),  1.f / (38.f * 38.f),
                             1.f / (14.f * 14.f)};
  int t = threadIdx.x;
  if (t < NIMG) {
    float p = 1.f;
#pragma unroll
    for (int s = 0; s < 5; ++s) {
      float sum = (s < 4) ? acc[(s * 2 + 1) * NIMG + t]
                          : acc[(s * 2 + 0) * NIMG + t];
      float m = sum * inv_npix[s];
      m = m > 0.f ? m : 0.f;
      p *= powf(m, wts[s]);
    }
    prods[t] = p;
  }
  __syncthreads();
  if (t == 0) {
    float s = 0.f;
    for (int i = 0; i < NIMG; ++i) s += prods[i];
    out[0] = 1.f - s / (float)NIMG;
  }
}

}  // namespace

extern "C" void kernel_launch(void* const* d_in, const int* in_sizes, int n_in,
                              void* d_out, int out_size, void* d_ws,
                              size_t ws_size, hipStream_t stream) {
  const float* X0 = (const float*)d_in[0];
  const float* Y0 = (const float*)d_in[1];
  float* out = (float*)d_out;
  float* ws = (float*)d_ws;

  const size_t L1 = (size_t)NIMG * 192 * 192;
  const size_t L2 = (size_t)NIMG * 96 * 96;
  const size_t L3 = (size_t)NIMG * 48 * 48;
  const size_t L4 = (size_t)NIMG * 24 * 24;

  float* x1 = ws;
  float* x2 = x1 + L1;
  float* x3 = x2 + L2;
  float* x4 = x3 + L3;
  float* y1 = x4 + L4;
  float* y2 = y1 + L1;
  float* y3 = y2 + L2;
  float* y4 = y3 + L3;
  float* acc = y4 + L4;  // 5*2*96 floats

  zero_acc<<<dim3(4), dim3(256), 0, stream>>>(acc, 10 * NIMG);

  pyramid_kernel<<<dim3(12, 12, NIMG), dim3(256), 0, stream>>>(
      X0, Y0, x1, y1, x2, y2, x3, y3, x4, y4);

  ssim_kernel<384, 384><<<dim3(12, 12, NIMG), dim3(256), 0, stream>>>(
      X0, Y0, acc + 0 * NIMG, acc + 1 * NIMG);
  ssim_kernel<192, 192><<<dim3(6, 6, NIMG), dim3(256), 0, stream>>>(
      x1, y1, acc + 2 * NIMG, acc + 3 * NIMG);
  ssim_kernel<96, 96><<<dim3(3, 3, NIMG), dim3(256), 0, stream>>>(
      x2, y2, acc + 4 * NIMG, acc + 5 * NIMG);
  ssim_kernel<48, 48><<<dim3(2, 2, NIMG), dim3(256), 0, stream>>>(
      x3, y3, acc + 6 * NIMG, acc + 7 * NIMG);
  ssim_kernel<24, 24><<<dim3(1, 1, NIMG), dim3(256), 0, stream>>>(
      x4, y4, acc + 8 * NIMG, acc + 9 * NIMG);

  final_kernel<<<dim3(1), dim3(128), 0, stream>>>(acc, out);
}

// Round 3
// 330.751 us; speedup vs baseline: 1.2232x; 1.0554x over previous
//
#include <hip/hip_runtime.h>
#include <math.h>

// MS-SSIM loss, fp32, (32,3,384,384), 5 scales, win=11 sigma=1.5, VALID.
// R3: LDS-free ssim kernel. vblur reads global directly (lane=column,
// wave=8-row group, sliding vertical accumulation in 40 regs); hblur via
// ds_bpermute lane shifts (conflict-free). All 5 scales fused into ONE
// launch via linearized tile index. 3 launches total.

namespace {

constexpr int NIMG = 96;            // B*C = 32*3
constexpr float C1c = 6.5025f;      // (0.01*255)^2
constexpr float C2c = 58.5225f;     // (0.03*255)^2

// gauss(11, sigma=1.5), normalized (matches expf path to fp32 ulp).
__device__ constexpr float GW[11] = {
    0.00102838f, 0.00759875f, 0.03600077f, 0.10936070f, 0.21300553f,
    0.26601172f,
    0.21300553f, 0.10936070f, 0.03600077f, 0.00759875f, 0.00102838f};

__device__ __forceinline__ float lane_shift(float v, int baddr, int k) {
  // value held by lane (lane+k) mod 64; constant k folds into DS offset.
  return __int_as_float(
      __builtin_amdgcn_ds_bpermute(baddr + (k << 2), __float_as_int(v)));
}

struct SPtrs {
  const float* x[5];
  const float* y[5];
};

// Tile: 54 output cols x 32 output rows. 256 threads = 4 waves;
// lane = col (64 incl. 10 halo), wave w = output rows 8w..8w+7.
// Tiles per scale: s0 7x12=84, s1 4x6=24, s2 2x3=6, s3 1x2=2, s4 1x1=1.
__global__ __launch_bounds__(256) void ssim_all(SPtrs sp,
                                                float* __restrict__ acc) {
  __shared__ float red[2][4];

  const int tile = blockIdx.x;
  int s;
  if (tile < 84) s = 0;
  else if (tile < 108) s = 1;
  else if (tile < 114) s = 2;
  else if (tile < 116) s = 3;
  else s = 4;
  const int tstart[5] = {0, 84, 108, 114, 116};
  const int HH[5] = {384, 192, 96, 48, 24};
  const int TXc[5] = {7, 4, 2, 1, 1};
  const int lt = tile - tstart[s];
  const int H = HH[s], W = H, OH = H - 10, OW = W - 10;
  const int tx = lt % TXc[s], ty = lt / TXc[s];
  const int img = blockIdx.z;
  const float* Xi = sp.x[s] + (size_t)img * H * W;
  const float* Yi = sp.y[s] + (size_t)img * H * W;

  const int t = threadIdx.x;
  const int lane = t & 63, wv = t >> 6;
  const int col = tx * 54 + lane;
  const int cin = col < W - 1 ? col : W - 1;
  const int row0 = ty * 32 + wv * 8;   // first output row of this wave

  // ---- vertical blur: 18 input rows -> 8 output rows x 5 channels ----
  float a0[8] = {}, a1[8] = {}, a2[8] = {}, a3[8] = {}, a4[8] = {};
#pragma unroll
  for (int j = 0; j < 18; ++j) {
    int rin = row0 + j;
    rin = rin < H - 1 ? rin : H - 1;
    float x = Xi[(size_t)rin * W + cin];
    float y = Yi[(size_t)rin * W + cin];
    float xx = x * x, yy = y * y, xy = x * y;
#pragma unroll
    for (int i = 0; i < 8; ++i) {
      const int k = j - i;
      if (k >= 0 && k <= 10) {
        const float wt = GW[k];
        a0[i] += wt * x;
        a1[i] += wt * y;
        a2[i] += wt * xx;
        a3[i] += wt * yy;
        a4[i] += wt * xy;
      }
    }
  }

  // ---- horizontal blur via lane shifts + SSIM map ----
  const int baddr = lane << 2;
  const bool colok = (lane < 54) && (col < OW);
  float ssim_s = 0.f, cs_s = 0.f;
#pragma unroll
  for (int i = 0; i < 8; ++i) {
    float b0 = GW[0] * a0[i], b1 = GW[0] * a1[i], b2 = GW[0] * a2[i],
          b3 = GW[0] * a3[i], b4 = GW[0] * a4[i];
#pragma unroll
    for (int k = 1; k <= 10; ++k) {
      b0 += GW[k] * lane_shift(a0[i], baddr, k);
      b1 += GW[k] * lane_shift(a1[i], baddr, k);
      b2 += GW[k] * lane_shift(a2[i], baddr, k);
      b3 += GW[k] * lane_shift(a3[i], baddr, k);
      b4 += GW[k] * lane_shift(a4[i], baddr, k);
    }
    if (colok && (row0 + i < OH)) {
      float mu1 = b0, mu2 = b1;
      float mu1sq = mu1 * mu1, mu2sq = mu2 * mu2, mu12 = mu1 * mu2;
      float s1 = b2 - mu1sq, s2v = b3 - mu2sq, s12 = b4 - mu12;
      float cs = (2.f * s12 + C2c) * __builtin_amdgcn_rcpf(s1 + s2v + C2c);
      float ss = (2.f * mu12 + C1c) *
                 __builtin_amdgcn_rcpf(mu1sq + mu2sq + C1c) * cs;
      cs_s += cs;
      ssim_s += ss;
    }
  }

  // ---- reduce: wave shuffle -> LDS -> 2 atomics/block ----
#pragma unroll
  for (int off = 32; off > 0; off >>= 1) {
    ssim_s += __shfl_down(ssim_s, off);
    cs_s += __shfl_down(cs_s, off);
  }
  if (lane == 0) { red[0][wv] = ssim_s; red[1][wv] = cs_s; }
  __syncthreads();
  if (t == 0) {
    atomicAdd(&acc[(2 * s + 0) * NIMG + img],
              red[0][0] + red[0][1] + red[0][2] + red[0][3]);
    atomicAdd(&acc[(2 * s + 1) * NIMG + img],
              red[1][0] + red[1][1] + red[1][2] + red[1][3]);
  }
}

// One launch builds all 4 pyramid levels for X and Y; block(0,0,0) also
// zeroes the accumulators (stream order guarantees done before ssim_all).
__global__ __launch_bounds__(256) void pyramid_kernel(
    const float* __restrict__ X, const float* __restrict__ Y,
    float* __restrict__ x1, float* __restrict__ y1,
    float* __restrict__ x2, float* __restrict__ y2,
    float* __restrict__ x3, float* __restrict__ y3,
    float* __restrict__ x4, float* __restrict__ y4,
    float* __restrict__ acc) {
  __shared__ float s1[16][17];
  __shared__ float s2[8][9];
  __shared__ float s3[4][5];
  const int img = blockIdx.z;
  const int gx0 = blockIdx.x * 32, gy0 = blockIdx.y * 32;
  const int t = threadIdx.x;
  const int r = t >> 4, ccol = t & 15;

  if (blockIdx.x == 0 && blockIdx.y == 0 && img == 0) {
    for (int i = t; i < 10 * NIMG; i += 256) acc[i] = 0.f;
  }

  const float* src[2] = {X + (size_t)img * 384 * 384,
                         Y + (size_t)img * 384 * 384};
  float* o1[2] = {x1 + (size_t)img * 192 * 192, y1 + (size_t)img * 192 * 192};
  float* o2[2] = {x2 + (size_t)img * 96 * 96,   y2 + (size_t)img * 96 * 96};
  float* o3[2] = {x3 + (size_t)img * 48 * 48,   y3 + (size_t)img * 48 * 48};
  float* o4[2] = {x4 + (size_t)img * 24 * 24,   y4 + (size_t)img * 24 * 24};

  for (int ch = 0; ch < 2; ++ch) {
    const float* S = src[ch];
    int gr = gy0 + 2 * r, gc = gx0 + 2 * ccol;
    float2 u = *(const float2*)&S[(size_t)gr * 384 + gc];
    float2 v = *(const float2*)&S[(size_t)(gr + 1) * 384 + gc];
    float l1 = 0.25f * (u.x + u.y + v.x + v.y);
    o1[ch][(size_t)(gy0 / 2 + r) * 192 + gx0 / 2 + ccol] = l1;
    s1[r][ccol] = l1;
    __syncthreads();
    if (t < 64) {
      int r2 = t >> 3, c2 = t & 7;
      float l2 = 0.25f * (s1[2 * r2][2 * c2] + s1[2 * r2][2 * c2 + 1] +
                          s1[2 * r2 + 1][2 * c2] + s1[2 * r2 + 1][2 * c2 + 1]);
      o2[ch][(size_t)(gy0 / 4 + r2) * 96 + gx0 / 4 + c2] = l2;
      s2[r2][c2] = l2;
    }
    __syncthreads();
    if (t < 16) {
      int r3 = t >> 2, c3 = t & 3;
      float l3 = 0.25f * (s2[2 * r3][2 * c3] + s2[2 * r3][2 * c3 + 1] +
                          s2[2 * r3 + 1][2 * c3] + s2[2 * r3 + 1][2 * c3 + 1]);
      o3[ch][(size_t)(gy0 / 8 + r3) * 48 + gx0 / 8 + c3] = l3;
      s3[r3][c3] = l3;
    }
    __syncthreads();
    if (t < 4) {
      int r4 = t >> 1, c4 = t & 1;
      float l4 = 0.25f * (s3[2 * r4][2 * c4] + s3[2 * r4][2 * c4 + 1] +
                          s3[2 * r4 + 1][2 * c4] + s3[2 * r4 + 1][2 * c4 + 1]);
      o4[ch][(size_t)(gy0 / 16 + r4) * 24 + gx0 / 16 + c4] = l4;
    }
    __syncthreads();
  }
}

// acc layout: acc[s*2+0][img] = ssim sum, acc[s*2+1][img] = cs sum.
__global__ void final_kernel(const float* __restrict__ acc,
                             float* __restrict__ out) {
  __shared__ float prods[NIMG];
  const float wts[5] = {0.0448f, 0.2856f, 0.3001f, 0.2363f, 0.1333f};
  const float inv_npix[5] = {1.f / (374.f * 374.f), 1.f / (182.f * 182.f),
                             1.f / (86.f * 86.f),  1.f / (38.f * 38.f),
                             1.f / (14.f * 14.f)};
  int t = threadIdx.x;
  if (t < NIMG) {
    float p = 1.f;
#pragma unroll
    for (int s = 0; s < 5; ++s) {
      float sum = (s < 4) ? acc[(s * 2 + 1) * NIMG + t]
                          : acc[(s * 2 + 0) * NIMG + t];
      float m = sum * inv_npix[s];
      m = m > 0.f ? m : 0.f;
      p *= powf(m, wts[s]);
    }
    prods[t] = p;
  }
  __syncthreads();
  if (t == 0) {
    float s = 0.f;
    for (int i = 0; i < NIMG; ++i) s += prods[i];
    out[0] = 1.f - s / (float)NIMG;
  }
}

}  // namespace

extern "C" void kernel_launch(void* const* d_in, const int* in_sizes, int n_in,
                              void* d_out, int out_size, void* d_ws,
                              size_t ws_size, hipStream_t stream) {
  const float* X0 = (const float*)d_in[0];
  const float* Y0 = (const float*)d_in[1];
  float* out = (float*)d_out;
  float* ws = (float*)d_ws;

  const size_t L1 = (size_t)NIMG * 192 * 192;
  const size_t L2 = (size_t)NIMG * 96 * 96;
  const size_t L3 = (size_t)NIMG * 48 * 48;
  const size_t L4 = (size_t)NIMG * 24 * 24;

  float* x1 = ws;
  float* x2 = x1 + L1;
  float* x3 = x2 + L2;
  float* x4 = x3 + L3;
  float* y1 = x4 + L4;
  float* y2 = y1 + L1;
  float* y3 = y2 + L2;
  float* y4 = y3 + L3;
  float* acc = y4 + L4;  // 5*2*96 floats

  pyramid_kernel<<<dim3(12, 12, NIMG), dim3(256), 0, stream>>>(
      X0, Y0, x1, y1, x2, y2, x3, y3, x4, y4, acc);

  SPtrs sp;
  sp.x[0] = X0; sp.x[1] = x1; sp.x[2] = x2; sp.x[3] = x3; sp.x[4] = x4;
  sp.y[0] = Y0; sp.y[1] = y1; sp.y[2] = y2; sp.y[3] = y3; sp.y[4] = y4;

  ssim_all<<<dim3(117, 1, NIMG), dim3(256), 0, stream>>>(sp, acc);

  final_kernel<<<dim3(1), dim3(128), 0, stream>>>(acc, out);
}

// Round 5
// 249.823 us; speedup vs baseline: 1.6194x; 1.3239x over previous
//
#include <hip/hip_runtime.h>
#include <math.h>

// MS-SSIM loss, fp32, (32,3,384,384), 5 scales, win=11 sigma=1.5, VALID.
// R5 = R4 with compile fix (powf instead of __exp2f in the one-shot final
// kernel). hblur lane-shifts on DPP wave_shl:1 (VALU pipe) instead of
// ds_bpermute (DS pipe, the R3 bottleneck). Barrier-free pyramid.

namespace {

constexpr int NIMG = 96;            // B*C = 32*3
constexpr float C1c = 6.5025f;      // (0.01*255)^2
constexpr float C2c = 58.5225f;     // (0.03*255)^2

// gauss(11, sigma=1.5), normalized (matches expf path to fp32 ulp).
__device__ constexpr float GW[11] = {
    0.00102838f, 0.00759875f, 0.03600077f, 0.10936070f, 0.21300553f,
    0.26601172f,
    0.21300553f, 0.10936070f, 0.03600077f, 0.00759875f, 0.00102838f};

// lane i <- lane i+1 (wave_shl:1, ctrl 0x130); lane 63 gets 0. VALU pipe.
__device__ __forceinline__ float wshl1(float v) {
  return __int_as_float(__builtin_amdgcn_mov_dpp(
      __float_as_int(v), 0x130, 0xF, 0xF, true));
}

struct SPtrs {
  const float* x[5];
  const float* y[5];
};

// Tile: 54 output cols x 32 output rows. 256 threads = 4 waves;
// lane = col (64 incl. 10 halo), wave w = output rows 8w..8w+7.
// Tiles per scale: s0 7x12=84, s1 4x6=24, s2 2x3=6, s3 1x2=2, s4 1x1=1.
__global__ __launch_bounds__(256) void ssim_all(SPtrs sp,
                                                float* __restrict__ acc) {
  __shared__ float red[2][4];

  const int tile = blockIdx.x;
  int s;
  if (tile < 84) s = 0;
  else if (tile < 108) s = 1;
  else if (tile < 114) s = 2;
  else if (tile < 116) s = 3;
  else s = 4;
  const int tstart[5] = {0, 84, 108, 114, 116};
  const int HH[5] = {384, 192, 96, 48, 24};
  const int TXc[5] = {7, 4, 2, 1, 1};
  const int lt = tile - tstart[s];
  const int H = HH[s], W = H, OH = H - 10, OW = W - 10;
  const int tx = lt % TXc[s], ty = lt / TXc[s];
  const int img = blockIdx.z;
  const float* Xi = sp.x[s] + (size_t)img * H * W;
  const float* Yi = sp.y[s] + (size_t)img * H * W;

  const int t = threadIdx.x;
  const int lane = t & 63, wv = t >> 6;
  const int col = tx * 54 + lane;
  const int cin = col < W - 1 ? col : W - 1;
  const int row0 = ty * 32 + wv * 8;   // first output row of this wave

  // ---- vertical blur: 18 input rows -> 8 output rows x 5 channels ----
  float a0[8] = {}, a1[8] = {}, a2[8] = {}, a3[8] = {}, a4[8] = {};
#pragma unroll
  for (int j = 0; j < 18; ++j) {
    int rin = row0 + j;
    rin = rin < H - 1 ? rin : H - 1;
    float x = Xi[(size_t)rin * W + cin];
    float y = Yi[(size_t)rin * W + cin];
    float xx = x * x, yy = y * y, xy = x * y;
#pragma unroll
    for (int i = 0; i < 8; ++i) {
      const int k = j - i;
      if (k >= 0 && k <= 10) {
        const float wt = GW[k];
        a0[i] += wt * x;
        a1[i] += wt * y;
        a2[i] += wt * xx;
        a3[i] += wt * yy;
        a4[i] += wt * xy;
      }
    }
  }

  // ---- horizontal blur via DPP wave_shl chains + SSIM map ----
  const bool colok = (lane < 54) && (col < OW);
  float ssim_s = 0.f, cs_s = 0.f;
#pragma unroll
  for (int i = 0; i < 8; ++i) {
    float t0 = a0[i], t1 = a1[i], t2 = a2[i], t3 = a3[i], t4 = a4[i];
    float b0 = GW[0] * t0, b1 = GW[0] * t1, b2 = GW[0] * t2,
          b3 = GW[0] * t3, b4 = GW[0] * t4;
#pragma unroll
    for (int k = 1; k <= 10; ++k) {
      t0 = wshl1(t0); b0 += GW[k] * t0;
      t1 = wshl1(t1); b1 += GW[k] * t1;
      t2 = wshl1(t2); b2 += GW[k] * t2;
      t3 = wshl1(t3); b3 += GW[k] * t3;
      t4 = wshl1(t4); b4 += GW[k] * t4;
    }
    if (colok && (row0 + i < OH)) {
      float mu1 = b0, mu2 = b1;
      float mu1sq = mu1 * mu1, mu2sq = mu2 * mu2, mu12 = mu1 * mu2;
      float s1 = b2 - mu1sq, s2v = b3 - mu2sq, s12 = b4 - mu12;
      float cs = (2.f * s12 + C2c) * __builtin_amdgcn_rcpf(s1 + s2v + C2c);
      float ss = (2.f * mu12 + C1c) *
                 __builtin_amdgcn_rcpf(mu1sq + mu2sq + C1c) * cs;
      cs_s += cs;
      ssim_s += ss;
    }
  }

  // ---- reduce: wave shuffle -> LDS -> 2 atomics/block ----
#pragma unroll
  for (int off = 32; off > 0; off >>= 1) {
    ssim_s += __shfl_down(ssim_s, off);
    cs_s += __shfl_down(cs_s, off);
  }
  if (lane == 0) { red[0][wv] = ssim_s; red[1][wv] = cs_s; }
  __syncthreads();
  if (t == 0) {
    atomicAdd(&acc[(2 * s + 0) * NIMG + img],
              red[0][0] + red[0][1] + red[0][2] + red[0][3]);
    atomicAdd(&acc[(2 * s + 1) * NIMG + img],
              red[1][0] + red[1][1] + red[1][2] + red[1][3]);
  }
}

// Barrier-free pyramid: each wave owns one 16x16 source tile and produces
// 8x8 L1, 4x4 L2, 2x2 L3, 1x1 L4 via shfl_xor 2x2 reductions.
// Block(0,0) also zeroes the accumulators.
__global__ __launch_bounds__(256) void pyramid_kernel(
    const float* __restrict__ X, const float* __restrict__ Y,
    float* __restrict__ x1, float* __restrict__ y1,
    float* __restrict__ x2, float* __restrict__ y2,
    float* __restrict__ x3, float* __restrict__ y3,
    float* __restrict__ x4, float* __restrict__ y4,
    float* __restrict__ acc) {
  const int img = blockIdx.y;
  const int t = threadIdx.x;
  if (blockIdx.x == 0 && img == 0) {
    for (int i = t; i < 10 * NIMG; i += 256) acc[i] = 0.f;
  }
  const int wv = t >> 6, lane = t & 63;
  const int tidx = blockIdx.x * 4 + wv;     // 0..575
  const int tx = tidx % 24, ty = tidx / 24;
  const int r = lane >> 3, c = lane & 7;    // 8x8 within wave

  const float* src[2] = {X + (size_t)img * 384 * 384,
                         Y + (size_t)img * 384 * 384};
  float* o1[2] = {x1 + (size_t)img * 192 * 192, y1 + (size_t)img * 192 * 192};
  float* o2[2] = {x2 + (size_t)img * 96 * 96,   y2 + (size_t)img * 96 * 96};
  float* o3[2] = {x3 + (size_t)img * 48 * 48,   y3 + (size_t)img * 48 * 48};
  float* o4[2] = {x4 + (size_t)img * 24 * 24,   y4 + (size_t)img * 24 * 24};

#pragma unroll
  for (int ch = 0; ch < 2; ++ch) {
    const float* S = src[ch];
    int gr = ty * 16 + 2 * r, gc = tx * 16 + 2 * c;
    float2 u = *(const float2*)&S[(size_t)gr * 384 + gc];
    float2 v = *(const float2*)&S[(size_t)(gr + 1) * 384 + gc];
    float l1 = 0.25f * (u.x + u.y + v.x + v.y);
    o1[ch][(size_t)(ty * 8 + r) * 192 + tx * 8 + c] = l1;

    float l2 = l1 + __shfl_xor(l1, 1);
    l2 = 0.25f * (l2 + __shfl_xor(l2, 8));
    if ((r & 1) == 0 && (c & 1) == 0)
      o2[ch][(size_t)(ty * 4 + (r >> 1)) * 96 + tx * 4 + (c >> 1)] = l2;

    float l3 = l2 + __shfl_xor(l2, 2);
    l3 = 0.25f * (l3 + __shfl_xor(l3, 16));
    if ((r & 3) == 0 && (c & 3) == 0)
      o3[ch][(size_t)(ty * 2 + (r >> 2)) * 48 + tx * 2 + (c >> 2)] = l3;

    float l4 = l3 + __shfl_xor(l3, 4);
    l4 = 0.25f * (l4 + __shfl_xor(l4, 32));
    if (lane == 0) o4[ch][(size_t)ty * 24 + tx] = l4;
  }
}

// acc layout: acc[s*2+0][img] = ssim sum, acc[s*2+1][img] = cs sum.
__global__ void final_kernel(const float* __restrict__ acc,
                             float* __restrict__ out) {
  __shared__ float prods[NIMG];
  const float wts[5] = {0.0448f, 0.2856f, 0.3001f, 0.2363f, 0.1333f};
  const float inv_npix[5] = {1.f / (374.f * 374.f), 1.f / (182.f * 182.f),
                             1.f / (86.f * 86.f),  1.f / (38.f * 38.f),
                             1.f / (14.f * 14.f)};
  int t = threadIdx.x;
  if (t < NIMG) {
    float p = 1.f;
#pragma unroll
    for (int s = 0; s < 5; ++s) {
      float sum = (s < 4) ? acc[(s * 2 + 1) * NIMG + t]
                          : acc[(s * 2 + 0) * NIMG + t];
      float m = sum * inv_npix[s];
      m = m > 0.f ? m : 0.f;
      p *= powf(m, wts[s]);
    }
    prods[t] = p;
  }
  __syncthreads();
  if (t == 0) {
    float s = 0.f;
    for (int i = 0; i < NIMG; ++i) s += prods[i];
    out[0] = 1.f - s / (float)NIMG;
  }
}

}  // namespace

extern "C" void kernel_launch(void* const* d_in, const int* in_sizes, int n_in,
                              void* d_out, int out_size, void* d_ws,
                              size_t ws_size, hipStream_t stream) {
  const float* X0 = (const float*)d_in[0];
  const float* Y0 = (const float*)d_in[1];
  float* out = (float*)d_out;
  float* ws = (float*)d_ws;

  const size_t L1 = (size_t)NIMG * 192 * 192;
  const size_t L2 = (size_t)NIMG * 96 * 96;
  const size_t L3 = (size_t)NIMG * 48 * 48;
  const size_t L4 = (size_t)NIMG * 24 * 24;

  float* x1 = ws;
  float* x2 = x1 + L1;
  float* x3 = x2 + L2;
  float* x4 = x3 + L3;
  float* y1 = x4 + L4;
  float* y2 = y1 + L1;
  float* y3 = y2 + L2;
  float* y4 = y3 + L3;
  float* acc = y4 + L4;  // 5*2*96 floats

  pyramid_kernel<<<dim3(144, NIMG), dim3(256), 0, stream>>>(
      X0, Y0, x1, y1, x2, y2, x3, y3, x4, y4, acc);

  SPtrs sp;
  sp.x[0] = X0; sp.x[1] = x1; sp.x[2] = x2; sp.x[3] = x3; sp.x[4] = x4;
  sp.y[0] = Y0; sp.y[1] = y1; sp.y[2] = y2; sp.y[3] = y3; sp.y[4] = y4;

  ssim_all<<<dim3(117, 1, NIMG), dim3(256), 0, stream>>>(sp, acc);

  final_kernel<<<dim3(1), dim3(128), 0, stream>>>(acc, out);
}

// Round 6
// 238.936 us; speedup vs baseline: 1.6932x; 1.0456x over previous
//
#include <hip/hip_runtime.h>
#include <math.h>

// MS-SSIM loss, fp32, (32,3,384,384), 5 scales, win=11 sigma=1.5, VALID.
// R6: 4-channel sufficient statistics (u=x+y, w=x-y, u^2, w^2 instead of
// x,y,xx,yy,xy) -> 20% fewer blur ops; channels paired as float2 so the
// compiler emits v_pk_fma_f32/v_pk_mul_f32 (2 FMAs/instr). Pyramid stores
// u,w planes (pooling is linear). hblur stays on DPP wave_shl chains.

namespace {

constexpr int NIMG = 96;            // B*C = 32*3
constexpr float TWO_C1 = 13.005f;   // 2*(0.01*255)^2
constexpr float TWO_C2 = 117.045f;  // 2*(0.03*255)^2

// gauss(11, sigma=1.5), normalized (matches expf path to fp32 ulp).
__device__ constexpr float GW[11] = {
    0.00102838f, 0.00759875f, 0.03600077f, 0.10936070f, 0.21300553f,
    0.26601172f,
    0.21300553f, 0.10936070f, 0.03600077f, 0.00759875f, 0.00102838f};

typedef float f2 __attribute__((ext_vector_type(2)));

__device__ __forceinline__ f2 pk(f2 a, f2 b, f2 c) {
#if __has_builtin(__builtin_elementwise_fma)
  return __builtin_elementwise_fma(a, b, c);
#else
  return a * b + c;
#endif
}

// lane i <- lane i+1 (wave_shl:1, ctrl 0x130); lane 63 gets 0. VALU pipe.
// Semantics HW-verified: R5 passed with absmax 0.0 using this helper.
__device__ __forceinline__ float wshl1(float v) {
  return __int_as_float(__builtin_amdgcn_mov_dpp(
      __float_as_int(v), 0x130, 0xF, 0xF, true));
}

__device__ __forceinline__ f2 wshl1v(f2 v) {
  f2 r;
  r.x = wshl1(v.x);
  r.y = wshl1(v.y);
  return r;
}

struct SPtrs {
  const float* x[5];   // s=0: X0; s>=1: U plane (x+y)
  const float* y[5];   // s=0: Y0; s>=1: W plane (x-y)
};

// Tile: 54 output cols x 32 output rows. 256 threads = 4 waves;
// lane = col (64 incl. 10 halo), wave w = output rows 8w..8w+7.
// Tiles per scale: s0 7x12=84, s1 4x6=24, s2 2x3=6, s3 1x2=2, s4 1x1=1.
__global__ __launch_bounds__(256) void ssim_all(SPtrs sp,
                                                float* __restrict__ acc) {
  __shared__ float red[2][4];

  const int tile = blockIdx.x;
  int s;
  if (tile < 84) s = 0;
  else if (tile < 108) s = 1;
  else if (tile < 114) s = 2;
  else if (tile < 116) s = 3;
  else s = 4;
  const int tstart[5] = {0, 84, 108, 114, 116};
  const int HH[5] = {384, 192, 96, 48, 24};
  const int TXc[5] = {7, 4, 2, 1, 1};
  const int lt = tile - tstart[s];
  const int H = HH[s], W = H, OH = H - 10, OW = W - 10;
  const int tx = lt % TXc[s], ty = lt / TXc[s];
  const int img = blockIdx.z;
  const float* Xi = sp.x[s] + (size_t)img * H * W;
  const float* Yi = sp.y[s] + (size_t)img * H * W;
  const bool base = (s == 0);

  const int t = threadIdx.x;
  const int lane = t & 63, wv = t >> 6;
  const int col = tx * 54 + lane;
  const int cin = col < W - 1 ? col : W - 1;
  const int row0 = ty * 32 + wv * 8;   // first output row of this wave

  // ---- vertical blur: 18 input rows -> 8 output rows x 2 f2-channels ----
  f2 A[8] = {}, B[8] = {};   // A=(blur u, blur w), B=(blur u^2, blur w^2)
#pragma unroll
  for (int j = 0; j < 18; ++j) {
    int rin = row0 + j;
    rin = rin < H - 1 ? rin : H - 1;
    float a = Xi[(size_t)rin * W + cin];
    float b = Yi[(size_t)rin * W + cin];
    f2 P;
    P.x = base ? a + b : a;   // u
    P.y = base ? a - b : b;   // w
    f2 Q = P * P;             // (u^2, w^2)  [v_pk_mul_f32]
#pragma unroll
    for (int i = 0; i < 8; ++i) {
      const int k = j - i;
      if (k >= 0 && k <= 10) {
        const f2 wt = GW[k];  // splat
        A[i] = pk(wt, P, A[i]);
        B[i] = pk(wt, Q, B[i]);
      }
    }
  }

  // ---- horizontal blur via DPP wave_shl chains + SSIM map ----
  const bool colok = (lane < 54) && (col < OW);
  float ssim_s = 0.f, cs_s = 0.f;
#pragma unroll
  for (int i = 0; i < 8; ++i) {
    f2 tA = A[i], tB = B[i];
    f2 bA = ((f2)GW[0]) * tA;
    f2 bB = ((f2)GW[0]) * tB;
#pragma unroll
    for (int k = 1; k <= 10; ++k) {
      const f2 wt = GW[k];
      tA = wshl1v(tA); bA = pk(wt, tA, bA);
      tB = wshl1v(tB); bB = pk(wt, tB, bB);
    }
    if (colok && (row0 + i < OH)) {
      // bA=(muU,muW), bB=(Eu2,Ew2)
      float m2u = bA.x * bA.x, m2w = bA.y * bA.y;
      float Pm = m2u - m2w;          // 4*mu1*mu2
      float Qm = m2u + m2w;          // 2*(mu1^2+mu2^2)
      float Am = bB.x - bB.y;        // 4*E[xy]
      float Bm = bB.x + bB.y;        // 2*(E[xx]+E[yy])
      float cs = (Am - Pm + TWO_C2) *
                 __builtin_amdgcn_rcpf(Bm - Qm + TWO_C2);
      float l = (Pm + TWO_C1) * __builtin_amdgcn_rcpf(Qm + TWO_C1);
      cs_s += cs;
      ssim_s += l * cs;
    }
  }

  // ---- reduce: wave shuffle -> LDS -> 2 atomics/block ----
#pragma unroll
  for (int off = 32; off > 0; off >>= 1) {
    ssim_s += __shfl_down(ssim_s, off);
    cs_s += __shfl_down(cs_s, off);
  }
  if (lane == 0) { red[0][wv] = ssim_s; red[1][wv] = cs_s; }
  __syncthreads();
  if (t == 0) {
    atomicAdd(&acc[(2 * s + 0) * NIMG + img],
              red[0][0] + red[0][1] + red[0][2] + red[0][3]);
    atomicAdd(&acc[(2 * s + 1) * NIMG + img],
              red[1][0] + red[1][1] + red[1][2] + red[1][3]);
  }
}

// Barrier-free pyramid producing u=x+y, w=x-y planes at levels 1..4.
// Each wave owns one 16x16 source tile -> 8x8 L1, 4x4 L2, 2x2 L3, 1x1 L4
// via shfl_xor 2x2 reductions. Block(0,*) of img 0 zeroes accumulators.
__global__ __launch_bounds__(256) void pyramid_kernel(
    const float* __restrict__ X, const float* __restrict__ Y,
    float* __restrict__ u1, float* __restrict__ w1,
    float* __restrict__ u2, float* __restrict__ w2,
    float* __restrict__ u3, float* __restrict__ w3,
    float* __restrict__ u4, float* __restrict__ w4,
    float* __restrict__ acc) {
  const int img = blockIdx.y;
  const int t = threadIdx.x;
  if (blockIdx.x == 0 && img == 0) {
    for (int i = t; i < 10 * NIMG; i += 256) acc[i] = 0.f;
  }
  const int wv = t >> 6, lane = t & 63;
  const int tidx = blockIdx.x * 4 + wv;     // 0..575
  const int tx = tidx % 24, ty = tidx / 24;
  const int r = lane >> 3, c = lane & 7;    // 8x8 within wave

  const float* Xs = X + (size_t)img * 384 * 384;
  const float* Ys = Y + (size_t)img * 384 * 384;
  float* o1[2] = {u1 + (size_t)img * 192 * 192, w1 + (size_t)img * 192 * 192};
  float* o2[2] = {u2 + (size_t)img * 96 * 96,   w2 + (size_t)img * 96 * 96};
  float* o3[2] = {u3 + (size_t)img * 48 * 48,   w3 + (size_t)img * 48 * 48};
  float* o4[2] = {u4 + (size_t)img * 24 * 24,   w4 + (size_t)img * 24 * 24};

  int gr = ty * 16 + 2 * r, gc = tx * 16 + 2 * c;
  float2 xu = *(const float2*)&Xs[(size_t)gr * 384 + gc];
  float2 xv = *(const float2*)&Xs[(size_t)(gr + 1) * 384 + gc];
  float2 yu = *(const float2*)&Ys[(size_t)gr * 384 + gc];
  float2 yv = *(const float2*)&Ys[(size_t)(gr + 1) * 384 + gc];
  float l1x = 0.25f * (xu.x + xu.y + xv.x + xv.y);
  float l1y = 0.25f * (yu.x + yu.y + yv.x + yv.y);
  float ch0 = l1x + l1y, ch1 = l1x - l1y;   // u, w at level 1
  float lv[2] = {ch0, ch1};

#pragma unroll
  for (int ch = 0; ch < 2; ++ch) {
    float l1 = lv[ch];
    o1[ch][(size_t)(ty * 8 + r) * 192 + tx * 8 + c] = l1;

    float l2 = l1 + __shfl_xor(l1, 1);
    l2 = 0.25f * (l2 + __shfl_xor(l2, 8));
    if ((r & 1) == 0 && (c & 1) == 0)
      o2[ch][(size_t)(ty * 4 + (r >> 1)) * 96 + tx * 4 + (c >> 1)] = l2;

    float l3 = l2 + __shfl_xor(l2, 2);
    l3 = 0.25f * (l3 + __shfl_xor(l3, 16));
    if ((r & 3) == 0 && (c & 3) == 0)
      o3[ch][(size_t)(ty * 2 + (r >> 2)) * 48 + tx * 2 + (c >> 2)] = l3;

    float l4 = l3 + __shfl_xor(l3, 4);
    l4 = 0.25f * (l4 + __shfl_xor(l4, 32));
    if (lane == 0) o4[ch][(size_t)ty * 24 + tx] = l4;
  }
}

// acc layout: acc[s*2+0][img] = ssim sum, acc[s*2+1][img] = cs sum.
__global__ void final_kernel(const float* __restrict__ acc,
                             float* __restrict__ out) {
  __shared__ float prods[NIMG];
  const float wts[5] = {0.0448f, 0.2856f, 0.3001f, 0.2363f, 0.1333f};
  const float inv_npix[5] = {1.f / (374.f * 374.f), 1.f / (182.f * 182.f),
                             1.f / (86.f * 86.f),  1.f / (38.f * 38.f),
                             1.f / (14.f * 14.f)};
  int t = threadIdx.x;
  if (t < NIMG) {
    float p = 1.f;
#pragma unroll
    for (int s = 0; s < 5; ++s) {
      float sum = (s < 4) ? acc[(s * 2 + 1) * NIMG + t]
                          : acc[(s * 2 + 0) * NIMG + t];
      float m = sum * inv_npix[s];
      m = m > 0.f ? m : 0.f;
      p *= powf(m, wts[s]);
    }
    prods[t] = p;
  }
  __syncthreads();
  if (t == 0) {
    float s = 0.f;
    for (int i = 0; i < NIMG; ++i) s += prods[i];
    out[0] = 1.f - s / (float)NIMG;
  }
}

}  // namespace

extern "C" void kernel_launch(void* const* d_in, const int* in_sizes, int n_in,
                              void* d_out, int out_size, void* d_ws,
                              size_t ws_size, hipStream_t stream) {
  const float* X0 = (const float*)d_in[0];
  const float* Y0 = (const float*)d_in[1];
  float* out = (float*)d_out;
  float* ws = (float*)d_ws;

  const size_t L1 = (size_t)NIMG * 192 * 192;
  const size_t L2 = (size_t)NIMG * 96 * 96;
  const size_t L3 = (size_t)NIMG * 48 * 48;
  const size_t L4 = (size_t)NIMG * 24 * 24;

  float* u1 = ws;
  float* u2 = u1 + L1;
  float* u3 = u2 + L2;
  float* u4 = u3 + L3;
  float* w1 = u4 + L4;
  float* w2 = w1 + L1;
  float* w3 = w2 + L2;
  float* w4 = w3 + L3;
  float* acc = w4 + L4;  // 5*2*96 floats

  pyramid_kernel<<<dim3(144, NIMG), dim3(256), 0, stream>>>(
      X0, Y0, u1, w1, u2, w2, u3, w3, u4, w4, acc);

  SPtrs sp;
  sp.x[0] = X0; sp.x[1] = u1; sp.x[2] = u2; sp.x[3] = u3; sp.x[4] = u4;
  sp.y[0] = Y0; sp.y[1] = w1; sp.y[2] = w2; sp.y[3] = w3; sp.y[4] = w4;

  ssim_all<<<dim3(117, 1, NIMG), dim3(256), 0, stream>>>(sp, acc);

  final_kernel<<<dim3(1), dim3(128), 0, stream>>>(acc, out);
}

// Round 7
// 238.891 us; speedup vs baseline: 1.6935x; 1.0002x over previous
//
#include <hip/hip_runtime.h>
#include <math.h>

// MS-SSIM loss, fp32, (32,3,384,384), 5 scales, win=11 sigma=1.5, VALID.
// R7: inline-asm v_pk_fma_f32/v_pk_mul_f32 (R6's ext-vector ops scalarized:
// measured ~2200 VALU instr/wave vs ~1000 expected); 16 output rows/wave
// (fewer loads+addr per output); uniform base/clamp branches; early-skip
// for out-of-range waves. hblur stays on DPP wave_shl chains.

namespace {

constexpr int NIMG = 96;            // B*C = 32*3
constexpr float TWO_C1 = 13.005f;   // 2*(0.01*255)^2
constexpr float TWO_C2 = 117.045f;  // 2*(0.03*255)^2

// gauss(11, sigma=1.5), normalized (matches expf path to fp32 ulp).
__device__ constexpr float GW[11] = {
    0.00102838f, 0.00759875f, 0.03600077f, 0.10936070f, 0.21300553f,
    0.26601172f,
    0.21300553f, 0.10936070f, 0.03600077f, 0.00759875f, 0.00102838f};

typedef float f2 __attribute__((ext_vector_type(2)));

// Packed fp32 math, forced via inline asm (VOP3P, gfx90a+).
__device__ __forceinline__ void pk_fma(f2& d, f2 a, f2 b) {
  asm("v_pk_fma_f32 %0, %1, %2, %0" : "+v"(d) : "v"(a), "v"(b));
}
__device__ __forceinline__ f2 pk_mul(f2 a, f2 b) {
  f2 d;
  asm("v_pk_mul_f32 %0, %1, %2" : "=v"(d) : "v"(a), "v"(b));
  return d;
}

// lane i <- lane i+1 (wave_shl:1, ctrl 0x130); lane 63 gets 0. VALU pipe.
// Semantics HW-verified (R5/R6 passed, absmax 0.0).
__device__ __forceinline__ float wshl1(float v) {
  return __int_as_float(__builtin_amdgcn_mov_dpp(
      __float_as_int(v), 0x130, 0xF, 0xF, true));
}
__device__ __forceinline__ f2 wshl1v(f2 v) {
  f2 r;
  r.x = wshl1(v.x);
  r.y = wshl1(v.y);
  return r;
}

struct SPtrs {
  const float* x[5];   // s=0: X0; s>=1: U plane (x+y)
  const float* y[5];   // s=0: Y0; s>=1: W plane (x-y)
};

template <bool BASE>
__device__ __forceinline__ void tap(int j, float a, float b, f2 (&A)[16],
                                    f2 (&B)[16], const f2 (&wtv)[11]) {
  f2 P;
  if (BASE) { P.x = a + b; P.y = a - b; }      // u, w
  else      { P.x = a;     P.y = b;     }
  f2 Q = pk_mul(P, P);                          // u^2, w^2
#pragma unroll
  for (int i = 0; i < 16; ++i) {
    const int k = j - i;                        // compile-time per unrolled j
    if (k >= 0 && k <= 10) {
      pk_fma(A[i], wtv[k], P);
      pk_fma(B[i], wtv[k], Q);
    }
  }
}

template <bool BASE, bool CLAMP>
__device__ __forceinline__ void vblur(const float* __restrict__ Xi,
                                      const float* __restrict__ Yi, int row0,
                                      int W, int H, int cin, f2 (&A)[16],
                                      f2 (&B)[16], const f2 (&wtv)[11]) {
#pragma unroll
  for (int j = 0; j < 26; ++j) {
    int rin = row0 + j;
    if (CLAMP) rin = rin < H - 1 ? rin : H - 1;
    float a = Xi[(size_t)rin * W + cin];
    float b = Yi[(size_t)rin * W + cin];
    tap<BASE>(j, a, b, A, B, wtv);
  }
}

// Tile: 54 output cols x 64 output rows. 256 threads = 4 waves;
// lane = col (64 incl. 10 halo), wave w = output rows 16w..16w+15.
// Tiles/scale: s0 7x6=42, s1 4x3=12, s2 2x2=4, s3 1, s4 1 (total 60).
__global__ __launch_bounds__(256) void ssim_all(SPtrs sp,
                                                float* __restrict__ acc) {
  __shared__ float red[2][4];

  const int tile = blockIdx.x;
  int s;
  if (tile < 42) s = 0;
  else if (tile < 54) s = 1;
  else if (tile < 58) s = 2;
  else if (tile < 59) s = 3;
  else s = 4;
  const int tstart[5] = {0, 42, 54, 58, 59};
  const int HH[5] = {384, 192, 96, 48, 24};
  const int TXc[5] = {7, 4, 2, 1, 1};
  const int lt = tile - tstart[s];
  const int H = HH[s], W = H, OH = H - 10, OW = W - 10;
  const int tx = lt % TXc[s], ty = lt / TXc[s];
  const int img = blockIdx.z;
  const float* Xi = sp.x[s] + (size_t)img * H * W;
  const float* Yi = sp.y[s] + (size_t)img * H * W;
  const bool base = (s == 0);

  const int t = threadIdx.x;
  const int lane = t & 63, wv = t >> 6;
  const int col = tx * 54 + lane;
  const int cin = col < W - 1 ? col : W - 1;
  const int row0 = ty * 64 + wv * 16;  // first output row of this wave

  f2 wtv[11];
#pragma unroll
  for (int k = 0; k < 11; ++k) { wtv[k].x = GW[k]; wtv[k].y = GW[k]; }

  float ssim_s = 0.f, cs_s = 0.f;

  if (row0 < OH) {                       // wave-uniform: skip idle waves
    f2 A[16] = {}, B[16] = {};           // (blur u, blur w), (blur u2, w2)
    const bool noclamp = (row0 + 25 <= H - 1);
    if (base) {
      if (noclamp) vblur<true, false>(Xi, Yi, row0, W, H, cin, A, B, wtv);
      else         vblur<true, true >(Xi, Yi, row0, W, H, cin, A, B, wtv);
    } else {
      if (noclamp) vblur<false, false>(Xi, Yi, row0, W, H, cin, A, B, wtv);
      else         vblur<false, true >(Xi, Yi, row0, W, H, cin, A, B, wtv);
    }

    // hblur via DPP wave_shl chains + SSIM map
    const bool colok = (lane < 54) && (col < OW);
#pragma unroll
    for (int i = 0; i < 16; ++i) {
      f2 tA = A[i], tB = B[i];
      f2 bA = pk_mul(wtv[0], tA);
      f2 bB = pk_mul(wtv[0], tB);
#pragma unroll
      for (int k = 1; k <= 10; ++k) {
        tA = wshl1v(tA); pk_fma(bA, wtv[k], tA);
        tB = wshl1v(tB); pk_fma(bB, wtv[k], tB);
      }
      if (colok && (row0 + i < OH)) {
        // bA=(muU,muW), bB=(Eu2,Ew2)
        float m2u = bA.x * bA.x, m2w = bA.y * bA.y;
        float Pm = m2u - m2w;          // 4*mu1*mu2
        float Qm = m2u + m2w;          // 2*(mu1^2+mu2^2)
        float Am = bB.x - bB.y;        // 4*E[xy]
        float Bm = bB.x + bB.y;        // 2*(E[xx]+E[yy])
        float cs = (Am - Pm + TWO_C2) *
                   __builtin_amdgcn_rcpf(Bm - Qm + TWO_C2);
        float l = (Pm + TWO_C1) * __builtin_amdgcn_rcpf(Qm + TWO_C1);
        cs_s += cs;
        ssim_s += l * cs;
      }
    }
  }

  // ---- reduce: wave shuffle -> LDS -> 2 atomics/block ----
#pragma unroll
  for (int off = 32; off > 0; off >>= 1) {
    ssim_s += __shfl_down(ssim_s, off);
    cs_s += __shfl_down(cs_s, off);
  }
  if (lane == 0) { red[0][wv] = ssim_s; red[1][wv] = cs_s; }
  __syncthreads();
  if (t == 0) {
    atomicAdd(&acc[(2 * s + 0) * NIMG + img],
              red[0][0] + red[0][1] + red[0][2] + red[0][3]);
    atomicAdd(&acc[(2 * s + 1) * NIMG + img],
              red[1][0] + red[1][1] + red[1][2] + red[1][3]);
  }
}

// Barrier-free pyramid producing u=x+y, w=x-y planes at levels 1..4.
// Each wave owns one 16x16 source tile -> 8x8 L1, 4x4 L2, 2x2 L3, 1x1 L4
// via shfl_xor 2x2 reductions. Block(0,*) of img 0 zeroes accumulators.
__global__ __launch_bounds__(256) void pyramid_kernel(
    const float* __restrict__ X, const float* __restrict__ Y,
    float* __restrict__ u1, float* __restrict__ w1,
    float* __restrict__ u2, float* __restrict__ w2,
    float* __restrict__ u3, float* __restrict__ w3,
    float* __restrict__ u4, float* __restrict__ w4,
    float* __restrict__ acc) {
  const int img = blockIdx.y;
  const int t = threadIdx.x;
  if (blockIdx.x == 0 && img == 0) {
    for (int i = t; i < 10 * NIMG; i += 256) acc[i] = 0.f;
  }
  const int wv = t >> 6, lane = t & 63;
  const int tidx = blockIdx.x * 4 + wv;     // 0..575
  const int tx = tidx % 24, ty = tidx / 24;
  const int r = lane >> 3, c = lane & 7;    // 8x8 within wave

  const float* Xs = X + (size_t)img * 384 * 384;
  const float* Ys = Y + (size_t)img * 384 * 384;
  float* o1[2] = {u1 + (size_t)img * 192 * 192, w1 + (size_t)img * 192 * 192};
  float* o2[2] = {u2 + (size_t)img * 96 * 96,   w2 + (size_t)img * 96 * 96};
  float* o3[2] = {u3 + (size_t)img * 48 * 48,   w3 + (size_t)img * 48 * 48};
  float* o4[2] = {u4 + (size_t)img * 24 * 24,   w4 + (size_t)img * 24 * 24};

  int gr = ty * 16 + 2 * r, gc = tx * 16 + 2 * c;
  float2 xu = *(const float2*)&Xs[(size_t)gr * 384 + gc];
  float2 xv = *(const float2*)&Xs[(size_t)(gr + 1) * 384 + gc];
  float2 yu = *(const float2*)&Ys[(size_t)gr * 384 + gc];
  float2 yv = *(const float2*)&Ys[(size_t)(gr + 1) * 384 + gc];
  float l1x = 0.25f * (xu.x + xu.y + xv.x + xv.y);
  float l1y = 0.25f * (yu.x + yu.y + yv.x + yv.y);
  float lv[2] = {l1x + l1y, l1x - l1y};     // u, w at level 1

#pragma unroll
  for (int ch = 0; ch < 2; ++ch) {
    float l1 = lv[ch];
    o1[ch][(size_t)(ty * 8 + r) * 192 + tx * 8 + c] = l1;

    float l2 = l1 + __shfl_xor(l1, 1);
    l2 = 0.25f * (l2 + __shfl_xor(l2, 8));
    if ((r & 1) == 0 && (c & 1) == 0)
      o2[ch][(size_t)(ty * 4 + (r >> 1)) * 96 + tx * 4 + (c >> 1)] = l2;

    float l3 = l2 + __shfl_xor(l2, 2);
    l3 = 0.25f * (l3 + __shfl_xor(l3, 16));
    if ((r & 3) == 0 && (c & 3) == 0)
      o3[ch][(size_t)(ty * 2 + (r >> 2)) * 48 + tx * 2 + (c >> 2)] = l3;

    float l4 = l3 + __shfl_xor(l3, 4);
    l4 = 0.25f * (l4 + __shfl_xor(l4, 32));
    if (lane == 0) o4[ch][(size_t)ty * 24 + tx] = l4;
  }
}

// acc layout: acc[s*2+0][img] = ssim sum, acc[s*2+1][img] = cs sum.
__global__ void final_kernel(const float* __restrict__ acc,
                             float* __restrict__ out) {
  __shared__ float prods[NIMG];
  const float wts[5] = {0.0448f, 0.2856f, 0.3001f, 0.2363f, 0.1333f};
  const float inv_npix[5] = {1.f / (374.f * 374.f), 1.f / (182.f * 182.f),
                             1.f / (86.f * 86.f),  1.f / (38.f * 38.f),
                             1.f / (14.f * 14.f)};
  int t = threadIdx.x;
  if (t < NIMG) {
    float p = 1.f;
#pragma unroll
    for (int s = 0; s < 5; ++s) {
      float sum = (s < 4) ? acc[(s * 2 + 1) * NIMG + t]
                          : acc[(s * 2 + 0) * NIMG + t];
      float m = sum * inv_npix[s];
      m = m > 0.f ? m : 0.f;
      p *= powf(m, wts[s]);
    }
    prods[t] = p;
  }
  __syncthreads();
  if (t == 0) {
    float s = 0.f;
    for (int i = 0; i < NIMG; ++i) s += prods[i];
    out[0] = 1.f - s / (float)NIMG;
  }
}

}  // namespace

extern "C" void kernel_launch(void* const* d_in, const int* in_sizes, int n_in,
                              void* d_out, int out_size, void* d_ws,
                              size_t ws_size, hipStream_t stream) {
  const float* X0 = (const float*)d_in[0];
  const float* Y0 = (const float*)d_in[1];
  float* out = (float*)d_out;
  float* ws = (float*)d_ws;

  const size_t L1 = (size_t)NIMG * 192 * 192;
  const size_t L2 = (size_t)NIMG * 96 * 96;
  const size_t L3 = (size_t)NIMG * 48 * 48;
  const size_t L4 = (size_t)NIMG * 24 * 24;

  float* u1 = ws;
  float* u2 = u1 + L1;
  float* u3 = u2 + L2;
  float* u4 = u3 + L3;
  float* w1 = u4 + L4;
  float* w2 = w1 + L1;
  float* w3 = w2 + L2;
  float* w4 = w3 + L3;
  float* acc = w4 + L4;  // 5*2*96 floats

  pyramid_kernel<<<dim3(144, NIMG), dim3(256), 0, stream>>>(
      X0, Y0, u1, w1, u2, w2, u3, w3, u4, w4, acc);

  SPtrs sp;
  sp.x[0] = X0; sp.x[1] = u1; sp.x[2] = u2; sp.x[3] = u3; sp.x[4] = u4;
  sp.y[0] = Y0; sp.y[1] = w1; sp.y[2] = w2; sp.y[3] = w3; sp.y[4] = w4;

  ssim_all<<<dim3(60, 1, NIMG), dim3(256), 0, stream>>>(sp, acc);

  final_kernel<<<dim3(1), dim3(128), 0, stream>>>(acc, out);
}

// Round 8
// 238.801 us; speedup vs baseline: 1.6942x; 1.0004x over previous
//
#include <hip/hip_runtime.h>
#include <math.h>

// MS-SSIM loss, fp32, (32,3,384,384), 5 scales, win=11 sigma=1.5, VALID.
// R8: column-pair f2 packing. Each lane owns 2 adjacent columns, so the
// hblur DPP chain advances 2 cols/step: 5 shift steps (20 movs) per TWO
// outputs vs R7's 10 steps (40 movs) per one. Even/odd tap cross-terms via
// VOP3P op_sel/op_sel_hi on v_pk_fma_f32 (splat-lo/hi src1, swapped weight
// pairs using G[k]=G[10-k] symmetry; 6 weight-pair regs). 8 rows/wave,
// launch_bounds(256,4) to pin VGPR<=128 (R7: compiler picked 48 and
// spilled the whole accumulator file).

namespace {

constexpr int NIMG = 96;            // B*C = 32*3
constexpr float TWO_C1 = 13.005f;   // 2*(0.01*255)^2
constexpr float TWO_C2 = 117.045f;  // 2*(0.03*255)^2

// gauss(11, sigma=1.5), normalized (matches expf path to fp32 ulp).
__device__ constexpr float GW[11] = {
    0.00102838f, 0.00759875f, 0.03600077f, 0.10936070f, 0.21300553f,
    0.26601172f,
    0.21300553f, 0.10936070f, 0.03600077f, 0.00759875f, 0.00102838f};

typedef float f2 __attribute__((ext_vector_type(2)));

// ---- VOP3P packed fp32 with op_sel variants ----
// op_sel[i]: half feeding LOW result (0=lo); op_sel_hi[i]: half feeding HIGH.
__device__ __forceinline__ f2 pk_mul(f2 a, f2 b) {
  f2 d;
  asm("v_pk_mul_f32 %0, %1, %2" : "=v"(d) : "v"(a), "v"(b));
  return d;
}
// d = a * splat_lo(b)  (init of hblur chain, j=0 even term)
__device__ __forceinline__ f2 pk_mul_s1lo(f2 a, f2 b) {
  f2 d;
  asm("v_pk_mul_f32 %0, %1, %2 op_sel:[0,0] op_sel_hi:[1,0]"
      : "=v"(d) : "v"(a), "v"(b));
  return d;
}
// d += splat_lo(q) * p   (vblur tap: weight splat from pair reg)
__device__ __forceinline__ void fma_w(f2& d, f2 q, f2 p) {
  asm("v_pk_fma_f32 %0, %1, %2, %0 op_sel:[0,0,0] op_sel_hi:[0,1,1]"
      : "+v"(d) : "v"(q), "v"(p));
}
// d += q * splat_lo(t)
__device__ __forceinline__ void fma_nl(f2& d, f2 q, f2 t) {
  asm("v_pk_fma_f32 %0, %1, %2, %0 op_sel:[0,0,0] op_sel_hi:[1,0,1]"
      : "+v"(d) : "v"(q), "v"(t));
}
// d += q * splat_hi(t)
__device__ __forceinline__ void fma_nh(f2& d, f2 q, f2 t) {
  asm("v_pk_fma_f32 %0, %1, %2, %0 op_sel:[0,1,0] op_sel_hi:[1,1,1]"
      : "+v"(d) : "v"(q), "v"(t));
}
// d += swap(q) * splat_lo(t)
__device__ __forceinline__ void fma_sl(f2& d, f2 q, f2 t) {
  asm("v_pk_fma_f32 %0, %1, %2, %0 op_sel:[1,0,0] op_sel_hi:[0,0,1]"
      : "+v"(d) : "v"(q), "v"(t));
}
// d += swap(q) * splat_hi(t)
__device__ __forceinline__ void fma_sh(f2& d, f2 q, f2 t) {
  asm("v_pk_fma_f32 %0, %1, %2, %0 op_sel:[1,1,0] op_sel_hi:[0,1,1]"
      : "+v"(d) : "v"(q), "v"(t));
}

// lane i <- lane i+1 (wave_shl:1); lane 63 gets 0. HW-verified (R5-R7).
__device__ __forceinline__ float wshl1(float v) {
  return __int_as_float(__builtin_amdgcn_mov_dpp(
      __float_as_int(v), 0x130, 0xF, 0xF, true));
}
__device__ __forceinline__ f2 wshl1v(f2 v) {
  f2 r;
  r.x = wshl1(v.x);
  r.y = wshl1(v.y);
  return r;
}

struct SPtrs {
  const float* x[5];   // s=0: X0; s>=1: U plane (x+y)
  const float* y[5];   // s=0: Y0; s>=1: W plane (x-y)
};

template <bool BASE, bool CLAMP>
__device__ __forceinline__ void vblur(const f2* __restrict__ PA,
                                      const f2* __restrict__ PB, int row0,
                                      int W2, int H, int cp, f2 (&AU)[8],
                                      f2 (&AW)[8], f2 (&BU)[8], f2 (&BW)[8],
                                      const f2 (&QQ)[6]) {
#pragma unroll
  for (int j = 0; j < 18; ++j) {
    int rin = row0 + j;
    if (CLAMP) rin = rin < H - 1 ? rin : H - 1;
    f2 pa = PA[(size_t)rin * W2 + cp];
    f2 pb = PB[(size_t)rin * W2 + cp];
    f2 Pu, Pw;
    if (BASE) { Pu = pa + pb; Pw = pa - pb; }   // u, w col-pairs
    else      { Pu = pa;      Pw = pb;      }
    f2 Qu = pk_mul(Pu, Pu), Qw = pk_mul(Pw, Pw);
#pragma unroll
    for (int i = 0; i < 8; ++i) {
      const int k = j - i;
      if (k >= 0 && k <= 10) {
        const int qi = k <= 5 ? k : 10 - k;     // G[k] = QQ[qi].x
        fma_w(AU[i], QQ[qi], Pu);
        fma_w(AW[i], QQ[qi], Pw);
        fma_w(BU[i], QQ[qi], Qu);
        fma_w(BW[i], QQ[qi], Qw);
      }
    }
  }
}

// Tile: 64 lanes x 2 cols = 128 input cols -> up to 118 outputs; 8 output
// rows per wave, 4 waves stacked = 32 rows/block.
// Grid/img: s0 4x12=48, s1 2x6=12, s2 3, s3 2, s4 1 (total 66).
__global__ __launch_bounds__(256, 4) void ssim_all(SPtrs sp,
                                                   float* __restrict__ acc) {
  __shared__ float red[2][4];

  const int tile = blockIdx.x;
  int s;
  if (tile < 48) s = 0;
  else if (tile < 60) s = 1;
  else if (tile < 63) s = 2;
  else if (tile < 65) s = 3;
  else s = 4;
  const int tstart[5] = {0, 48, 60, 63, 65};
  const int HH[5] = {384, 192, 96, 48, 24};
  const int NTX[5] = {4, 2, 1, 1, 1};
  const int TWM[5] = {94, 92, 86, 38, 14};
  const int lt = tile - tstart[s];
  const int H = HH[s], W = H, OH = H - 10, OW = W - 10, W2 = W >> 1;
  const int tx = lt % NTX[s], by = lt / NTX[s];
  const int x0 = tx * TWM[s];
  const int tw = (TWM[s] < OW - x0) ? TWM[s] : OW - x0;
  const int img = blockIdx.z;
  const f2* PA = (const f2*)sp.x[s] + (size_t)img * H * W2;
  const f2* PB = (const f2*)sp.y[s] + (size_t)img * H * W2;

  const int t = threadIdx.x;
  const int lane = t & 63, wv = t >> 6;
  int cp = (x0 >> 1) + lane;
  cp = cp < W2 - 1 ? cp : W2 - 1;
  const int row0 = by * 32 + wv * 8;

  // Weight pairs QQ[n] = (G[n], G[n-1]), G[-1]=0. All other weight forms
  // derived via op_sel (splat-lo / swap) using G[k] = G[10-k].
  f2 QQ[6];
  QQ[0].x = GW[0]; QQ[0].y = 0.f;
#pragma unroll
  for (int n = 1; n < 6; ++n) { QQ[n].x = GW[n]; QQ[n].y = GW[n - 1]; }

  float ssim_s = 0.f, cs_s = 0.f;

  if (row0 < OH) {
    f2 AU[8] = {}, AW[8] = {}, BU[8] = {}, BW[8] = {};
    const bool noclamp = (row0 + 17 <= H - 1);
    if (s == 0) {
      if (noclamp) vblur<true, false>(PA, PB, row0, W2, H, cp, AU, AW, BU, BW, QQ);
      else         vblur<true, true >(PA, PB, row0, W2, H, cp, AU, AW, BU, BW, QQ);
    } else {
      if (noclamp) vblur<false, false>(PA, PB, row0, W2, H, cp, AU, AW, BU, BW, QQ);
      else         vblur<false, true >(PA, PB, row0, W2, H, cp, AU, AW, BU, BW, QQ);
    }

    // hblur: 2 outputs/lane, 5 two-col shift steps.
    // O.x = sum_k G[k]*V[2c+k], O.y = sum_k G[k]*V[2c+1+k]; contribution of
    // t_j=(e,o)=(V[2c+2j],V[2c+2j+1]): (G[2j],G[2j-1])*e + (G[2j+1],G[2j])*o.
    auto hb = [&QQ](f2 tt) -> f2 {
      f2 h = pk_mul_s1lo(QQ[0], tt);   // j=0: (G0,0)*e
      fma_nh(h, QQ[1], tt);            // j=0: (G1,G0)*o
      tt = wshl1v(tt);
      fma_nl(h, QQ[2], tt);            // j=1: (G2,G1)*e
      fma_nh(h, QQ[3], tt);            // j=1: (G3,G2)*o
      tt = wshl1v(tt);
      fma_nl(h, QQ[4], tt);            // j=2: (G4,G3)*e
      fma_nh(h, QQ[5], tt);            // j=2: (G5,G4)*o
      tt = wshl1v(tt);
      fma_sl(h, QQ[5], tt);            // j=3: (G6,G5)=(G4,G5)=swap(QQ5)
      fma_sh(h, QQ[4], tt);            // j=3: (G7,G6)=(G3,G4)=swap(QQ4)
      tt = wshl1v(tt);
      fma_sl(h, QQ[3], tt);            // j=4: (G8,G7)=swap(QQ3)
      fma_sh(h, QQ[2], tt);            // j=4: (G9,G8)=swap(QQ2)
      tt = wshl1v(tt);
      fma_sl(h, QQ[1], tt);            // j=5: (G10,G9)=swap(QQ1)
      fma_sh(h, QQ[0], tt);            // j=5: (0,G10)=swap(QQ0)
      return h;
    };

    const bool vx = (2 * lane) < tw;
    const bool vy = (2 * lane + 1) < tw;
#pragma unroll
    for (int i = 0; i < 8; ++i) {
      if (row0 + i < OH) {
        f2 bU = hb(AU[i]), bW = hb(AW[i]);
        f2 bU2 = hb(BU[i]), bW2 = hb(BW[i]);
        f2 m2u = pk_mul(bU, bU), m2w = pk_mul(bW, bW);
        f2 Pm = m2u - m2w;           // 4*mu1*mu2
        f2 Qm = m2u + m2w;           // 2*(mu1^2+mu2^2)
        f2 Am = bU2 - bW2;           // 4*E[xy]
        f2 Bm = bU2 + bW2;           // 2*(E[xx]+E[yy])
        float csx = (Am.x - Pm.x + TWO_C2) *
                    __builtin_amdgcn_rcpf(Bm.x - Qm.x + TWO_C2);
        float lx = (Pm.x + TWO_C1) * __builtin_amdgcn_rcpf(Qm.x + TWO_C1);
        float csy = (Am.y - Pm.y + TWO_C2) *
                    __builtin_amdgcn_rcpf(Bm.y - Qm.y + TWO_C2);
        float ly = (Pm.y + TWO_C1) * __builtin_amdgcn_rcpf(Qm.y + TWO_C1);
        if (vx) { cs_s += csx; ssim_s += lx * csx; }
        if (vy) { cs_s += csy; ssim_s += ly * csy; }
      }
    }
  }

  // ---- reduce: wave shuffle -> LDS -> 2 atomics/block ----
#pragma unroll
  for (int off = 32; off > 0; off >>= 1) {
    ssim_s += __shfl_down(ssim_s, off);
    cs_s += __shfl_down(cs_s, off);
  }
  if (lane == 0) { red[0][wv] = ssim_s; red[1][wv] = cs_s; }
  __syncthreads();
  if (t == 0) {
    atomicAdd(&acc[(2 * s + 0) * NIMG + img],
              red[0][0] + red[0][1] + red[0][2] + red[0][3]);
    atomicAdd(&acc[(2 * s + 1) * NIMG + img],
              red[1][0] + red[1][1] + red[1][2] + red[1][3]);
  }
}

// Barrier-free pyramid producing u=x+y, w=x-y planes at levels 1..4.
// Each wave owns one 16x16 source tile -> 8x8 L1, 4x4 L2, 2x2 L3, 1x1 L4
// via shfl_xor 2x2 reductions. Block(0,*) of img 0 zeroes accumulators.
__global__ __launch_bounds__(256) void pyramid_kernel(
    const float* __restrict__ X, const float* __restrict__ Y,
    float* __restrict__ u1, float* __restrict__ w1,
    float* __restrict__ u2, float* __restrict__ w2,
    float* __restrict__ u3, float* __restrict__ w3,
    float* __restrict__ u4, float* __restrict__ w4,
    float* __restrict__ acc) {
  const int img = blockIdx.y;
  const int t = threadIdx.x;
  if (blockIdx.x == 0 && img == 0) {
    for (int i = t; i < 10 * NIMG; i += 256) acc[i] = 0.f;
  }
  const int wv = t >> 6, lane = t & 63;
  const int tidx = blockIdx.x * 4 + wv;     // 0..575
  const int tx = tidx % 24, ty = tidx / 24;
  const int r = lane >> 3, c = lane & 7;    // 8x8 within wave

  const float* Xs = X + (size_t)img * 384 * 384;
  const float* Ys = Y + (size_t)img * 384 * 384;
  float* o1[2] = {u1 + (size_t)img * 192 * 192, w1 + (size_t)img * 192 * 192};
  float* o2[2] = {u2 + (size_t)img * 96 * 96,   w2 + (size_t)img * 96 * 96};
  float* o3[2] = {u3 + (size_t)img * 48 * 48,   w3 + (size_t)img * 48 * 48};
  float* o4[2] = {u4 + (size_t)img * 24 * 24,   w4 + (size_t)img * 24 * 24};

  int gr = ty * 16 + 2 * r, gc = tx * 16 + 2 * c;
  float2 xu = *(const float2*)&Xs[(size_t)gr * 384 + gc];
  float2 xv = *(const float2*)&Xs[(size_t)(gr + 1) * 384 + gc];
  float2 yu = *(const float2*)&Ys[(size_t)gr * 384 + gc];
  float2 yv = *(const float2*)&Ys[(size_t)(gr + 1) * 384 + gc];
  float l1x = 0.25f * (xu.x + xu.y + xv.x + xv.y);
  float l1y = 0.25f * (yu.x + yu.y + yv.x + yv.y);
  float lv[2] = {l1x + l1y, l1x - l1y};     // u, w at level 1

#pragma unroll
  for (int ch = 0; ch < 2; ++ch) {
    float l1 = lv[ch];
    o1[ch][(size_t)(ty * 8 + r) * 192 + tx * 8 + c] = l1;

    float l2 = l1 + __shfl_xor(l1, 1);
    l2 = 0.25f * (l2 + __shfl_xor(l2, 8));
    if ((r & 1) == 0 && (c & 1) == 0)
      o2[ch][(size_t)(ty * 4 + (r >> 1)) * 96 + tx * 4 + (c >> 1)] = l2;

    float l3 = l2 + __shfl_xor(l2, 2);
    l3 = 0.25f * (l3 + __shfl_xor(l3, 16));
    if ((r & 3) == 0 && (c & 3) == 0)
      o3[ch][(size_t)(ty * 2 + (r >> 2)) * 48 + tx * 2 + (c >> 2)] = l3;

    float l4 = l3 + __shfl_xor(l3, 4);
    l4 = 0.25f * (l4 + __shfl_xor(l4, 32));
    if (lane == 0) o4[ch][(size_t)ty * 24 + tx] = l4;
  }
}

// acc layout: acc[s*2+0][img] = ssim sum, acc[s*2+1][img] = cs sum.
__global__ void final_kernel(const float* __restrict__ acc,
                             float* __restrict__ out) {
  __shared__ float prods[NIMG];
  const float wts[5] = {0.0448f, 0.2856f, 0.3001f, 0.2363f, 0.1333f};
  const float inv_npix[5] = {1.f / (374.f * 374.f), 1.f / (182.f * 182.f),
                             1.f / (86.f * 86.f),  1.f / (38.f * 38.f),
                             1.f / (14.f * 14.f)};
  int t = threadIdx.x;
  if (t < NIMG) {
    float p = 1.f;
#pragma unroll
    for (int s = 0; s < 5; ++s) {
      float sum = (s < 4) ? acc[(s * 2 + 1) * NIMG + t]
                          : acc[(s * 2 + 0) * NIMG + t];
      float m = sum * inv_npix[s];
      m = m > 0.f ? m : 0.f;
      p *= powf(m, wts[s]);
    }
    prods[t] = p;
  }
  __syncthreads();
  if (t == 0) {
    float s = 0.f;
    for (int i = 0; i < NIMG; ++i) s += prods[i];
    out[0] = 1.f - s / (float)NIMG;
  }
}

}  // namespace

extern "C" void kernel_launch(void* const* d_in, const int* in_sizes, int n_in,
                              void* d_out, int out_size, void* d_ws,
                              size_t ws_size, hipStream_t stream) {
  const float* X0 = (const float*)d_in[0];
  const float* Y0 = (const float*)d_in[1];
  float* out = (float*)d_out;
  float* ws = (float*)d_ws;

  const size_t L1 = (size_t)NIMG * 192 * 192;
  const size_t L2 = (size_t)NIMG * 96 * 96;
  const size_t L3 = (size_t)NIMG * 48 * 48;
  const size_t L4 = (size_t)NIMG * 24 * 24;

  float* u1 = ws;
  float* u2 = u1 + L1;
  float* u3 = u2 + L2;
  float* u4 = u3 + L3;
  float* w1 = u4 + L4;
  float* w2 = w1 + L1;
  float* w3 = w2 + L2;
  float* w4 = w3 + L3;
  float* acc = w4 + L4;  // 5*2*96 floats

  pyramid_kernel<<<dim3(144, NIMG), dim3(256), 0, stream>>>(
      X0, Y0, u1, w1, u2, w2, u3, w3, u4, w4, acc);

  SPtrs sp;
  sp.x[0] = X0; sp.x[1] = u1; sp.x[2] = u2; sp.x[3] = u3; sp.x[4] = u4;
  sp.y[0] = Y0; sp.y[1] = w1; sp.y[2] = w2; sp.y[3] = w3; sp.y[4] = w4;

  ssim_all<<<dim3(66, 1, NIMG), dim3(256), 0, stream>>>(sp, acc);

  final_kernel<<<dim3(1), dim3(128), 0, stream>>>(acc, out);
}